// Round 1
// baseline (764.569 us; speedup 1.0000x reference)
//
#include <hip/hip_runtime.h>
#include <math.h>

typedef __attribute__((ext_vector_type(8)))  __bf16 bf16x8;
typedef __attribute__((ext_vector_type(16))) float  f32x16;
typedef __attribute__((ext_vector_type(4)))  float  f32x4;
typedef __attribute__((ext_vector_type(4)))  int    i32x4;
typedef __attribute__((ext_vector_type(4)))  unsigned u32x4;

union FR { bf16x8 v; u32x4 q; unsigned u[4]; };

__device__ inline f32x16 MF(bf16x8 a, bf16x8 b, f32x16 c) {
    return __builtin_amdgcn_mfma_f32_32x32x16_bf16(a, b, c, 0, 0, 0);
}
__device__ inline unsigned pk(float a, float b) {
    unsigned ua = (__builtin_bit_cast(unsigned, a) + 0x8000u) >> 16;
    unsigned ub = (__builtin_bit_cast(unsigned, b) + 0x8000u) >> 16;
    return ua | (ub << 16);
}
__device__ inline unsigned short bfr(float a) {
    return (unsigned short)((__builtin_bit_cast(unsigned, a) + 0x8000u) >> 16);
}
__device__ inline float ubf(unsigned short s) {
    return __builtin_bit_cast(float, (unsigned)s << 16);
}
// exact-erf GELU via Abramowitz-Stegun 7.1.26 (|err| < 1.5e-7)
__device__ inline float gelu_f(float g) {
    float z  = g * 0.70710678118654752f;
    float az = fabsf(z);
    float t  = 1.0f / (1.0f + 0.3275911f * az);
    float poly = t*(0.254829592f + t*(-0.284496736f + t*(1.421413741f +
                 t*(-1.453152027f + t*1.061405429f))));
    float er = 1.0f - poly * __expf(-az * az);
    er = (z < 0.f) ? -er : er;
    return 0.5f * g * (1.0f + er);
}

// ---------------- k0: pack Wkv + o2w into MFMA B-frag order, pack bkv ---------
// wkvpk: [kt12][nt12][l64][q4] uints ; frag elem = W[nt*32+(l&31)][kt*16+(l>>5)*8+2q..+1]
__global__ void k0_pack(const float* __restrict__ qkv_w, const float* __restrict__ qkv_b,
                        const float* __restrict__ o2w,
                        unsigned* __restrict__ wkvpk, unsigned* __restrict__ o2pk,
                        float* __restrict__ bkv)
{
    int idx = blockIdx.x * 256 + threadIdx.x;
    if (idx < 36864) {
        int kt = idx / 3072, r = idx % 3072, nt = r / 256, r3 = r % 256;
        int l = r3 >> 2, q = r3 & 3;
        int c  = kt * 16 + (l >> 5) * 8 + q * 2;
        int rp = nt * 32 + (l & 31);
        int row = (rp >> 6) * 96 + 32 + (rp & 63);       // k rows 32..63, v rows 64..95
        wkvpk[idx] = pk(qkv_w[row * 192 + c], qkv_w[row * 192 + c + 1]);
    } else if (idx < 55296) {
        int i2 = idx - 36864;
        int kt = i2 / 1536, r = i2 % 1536, jt = r / 256, r3 = r % 256;
        int l = r3 >> 2, q = r3 & 3;
        int jj = kt * 16 + (l >> 5) * 8 + q * 2;
        int j  = jt * 32 + (l & 31);
        o2pk[i2] = pk(o2w[j * 192 + jj], o2w[j * 192 + jj + 1]);
    } else if (idx < 55680) {
        int rp = idx - 55296;
        bkv[rp] = qkv_b[(rp >> 6) * 96 + 32 + (rp & 63)];
    }
}

// ---------------- k1: FUSED k/v projection + LN + k'^T v' Gram ----------------
// Replaces k1a + k1b. Never writes raw k/v to HBM.
// grid 512 x 256. Block = 4 waves; wave = 32-px strip, 4 strips/wave (16/block).
// Per head: 24 proj MFMAs -> C-layout acc; per-wave LDS transpose for per-pixel
// LN stats (f32, ddof=1); normalize in-register; shfl_xor(32) half-exchange to
// build A/B frags; 2 MFMAs accumulate S1 = sum_p k'[p,d] v'[p,e] into block LDS
// (ds_add_f32). LN affine folded out: reducer k1c applies
//   kv = (kw*vw*S1 + kw*vb*sk + kb*vw*sv)/n + kb*vb.
// Per-block partials (6912 floats) -> d_out scratch (14.2 MB), no global atomics.
__global__ __launch_bounds__(256, 2)
void k1(const float* __restrict__ x, const u32x4* __restrict__ Wpk,
        const float* __restrict__ bkv, float* __restrict__ part)
{
    __shared__ __align__(16) float s1[6][16][64];     // 24576 B  S1 accum (C-layout)
    __shared__ float skv[12][64];                     //  3072 B  [h]=k, [6+h]=v partial sums
    __shared__ __align__(16) float scr[4][64 * 34];   // 34816 B  per-wave transpose scratch
    __shared__ __align__(8)  float st[4][2][32][2];   //  2048 B  per-wave (m,inv) per (tile,px)

    const int tid = threadIdx.x;
    const int wid = tid >> 6, lane = tid & 63;
    const int col = lane & 31, lh = lane >> 5;
    const int g = blockIdx.x, b = g >> 7, gb = g & 127;

    for (int i = tid; i < 6144; i += 256) ((float*)s1)[i] = 0.f;
    for (int i = tid; i < 768;  i += 256) ((float*)skv)[i] = 0.f;
    __syncthreads();

    float* sc  = scr[wid];
    float* stw = (float*)st[wid];

    for (int it = 0; it < 4; ++it) {
        const int sp = gb * 16 + wid * 4 + it;
        const float* xr = x + ((long)(b * 65536 + sp * 32 + col)) * 192 + lh * 8;
        FR afr[12];
#pragma unroll
        for (int kt = 0; kt < 12; ++kt) {
            f32x4 a0 = *(const f32x4*)(xr + kt * 16);
            f32x4 a1 = *(const f32x4*)(xr + kt * 16 + 4);
            afr[kt].u[0] = pk(a0.x, a0.y); afr[kt].u[1] = pk(a0.z, a0.w);
            afr[kt].u[2] = pk(a1.x, a1.y); afr[kt].u[3] = pk(a1.z, a1.w);
        }

        for (int h = 0; h < 6; ++h) {
            // ---- projection: k-tile (nt=2h) and v-tile (nt=2h+1), C-layout ----
            f32x16 acck = (f32x16)(bkv[(2 * h) * 32 + col]);
            f32x16 accv = (f32x16)(bkv[(2 * h + 1) * 32 + col]);
#pragma unroll
            for (int kt = 0; kt < 12; ++kt) {
                FR bk_, bv_;
                bk_.q = Wpk[(kt * 12 + 2 * h) * 64 + lane];
                bv_.q = Wpk[(kt * 12 + 2 * h + 1) * 64 + lane];
                acck = MF(afr[kt].v, bk_.v, acck);
                accv = MF(afr[kt].v, bv_.v, accv);
            }
            // ---- scratch write: [ch 0..31 k | 32..63 v][px pad34] f32 ----
            // C-layout: row p = (r&3)+4*lh+8*(r>>2); even-r pairs are (p,p+1).
#pragma unroll
            for (int r = 0; r < 16; r += 2) {
                int p = (r & 3) + 4 * lh + 8 * (r >> 2);
                *(float2*)&sc[col * 34 + p]        = make_float2(acck[r], acck[r + 1]);
                *(float2*)&sc[(32 + col) * 34 + p] = make_float2(accv[r], accv[r + 1]);
            }
            __builtin_amdgcn_wave_barrier();   // DS same-wave in-order; block reordering
            // ---- stats: lane job = (tile lh, pixel col): mean + 1/(std+eps) ----
            {
                const float* cb = sc + (lh * 32) * 34 + col;
                float s = 0.f, s2 = 0.f;
#pragma unroll
                for (int ch = 0; ch < 32; ++ch) {
                    float v = cb[ch * 34];
                    s += v; s2 = fmaf(v, v, s2);
                }
                float m   = s * (1.f / 32.f);
                float var = fmaxf((s2 - 32.f * m * m) * (1.f / 31.f), 0.f);
                float inv = 1.f / (sqrtf(var) + 1e-5f);
                *(float2*)&stw[(lh * 32 + col) * 2] = make_float2(m, inv);
            }
            __builtin_amdgcn_wave_barrier();
            // ---- normalize (no affine) + pack bf16 pixel-pairs ----
            float skl = 0.f, svl = 0.f;
            unsigned pkk[8], pkv[8];
#pragma unroll
            for (int j = 0; j < 8; ++j) {
                int r0 = 2 * j;
                int p0 = (r0 & 3) + 4 * lh + 8 * (r0 >> 2);
                float2 a0 = *(float2*)&stw[p0 * 2];
                float2 a1 = *(float2*)&stw[(p0 + 1) * 2];
                float2 c0 = *(float2*)&stw[(32 + p0) * 2];
                float2 c1 = *(float2*)&stw[(32 + p0 + 1) * 2];
                float k0 = (acck[r0]     - a0.x) * a0.y;
                float k1v = (acck[r0 + 1] - a1.x) * a1.y;
                float v0 = (accv[r0]     - c0.x) * c0.y;
                float v1 = (accv[r0 + 1] - c1.x) * c1.y;
                skl += k0 + k1v; svl += v0 + v1;
                pkk[j] = pk(k0, k1v); pkv[j] = pk(v0, v1);
            }
            atomicAdd(&skv[h][lane], skl);
            atomicAdd(&skv[6 + h][lane], svl);
            // ---- half-wave exchange: C-layout pixel sets -> frag k-slots ----
            unsigned ka0 = __shfl_xor((int)(lh ? pkk[0] : pkk[2]), 32);
            unsigned ka1 = __shfl_xor((int)(lh ? pkk[1] : pkk[3]), 32);
            unsigned ka2 = __shfl_xor((int)(lh ? pkk[4] : pkk[6]), 32);
            unsigned ka3 = __shfl_xor((int)(lh ? pkk[5] : pkk[7]), 32);
            unsigned vb0 = __shfl_xor((int)(lh ? pkv[0] : pkv[2]), 32);
            unsigned vb1 = __shfl_xor((int)(lh ? pkv[1] : pkv[3]), 32);
            unsigned vb2 = __shfl_xor((int)(lh ? pkv[4] : pkv[6]), 32);
            unsigned vb3 = __shfl_xor((int)(lh ? pkv[5] : pkv[7]), 32);
            FR A0, A1, B0, B1;
            A0.u[0] = lh ? ka0 : pkk[0]; A0.u[1] = lh ? ka1 : pkk[1];
            A0.u[2] = lh ? pkk[2] : ka0; A0.u[3] = lh ? pkk[3] : ka1;
            A1.u[0] = lh ? ka2 : pkk[4]; A1.u[1] = lh ? ka3 : pkk[5];
            A1.u[2] = lh ? pkk[6] : ka2; A1.u[3] = lh ? pkk[7] : ka3;
            B0.u[0] = lh ? vb0 : pkv[0]; B0.u[1] = lh ? vb1 : pkv[1];
            B0.u[2] = lh ? pkv[2] : vb0; B0.u[3] = lh ? pkv[3] : vb1;
            B1.u[0] = lh ? vb2 : pkv[4]; B1.u[1] = lh ? vb3 : pkv[5];
            B1.u[2] = lh ? pkv[6] : vb2; B1.u[3] = lh ? pkv[7] : vb3;
            // ---- S1 += k'^T v' : D[d,e], contraction over the 32 pixels ----
            f32x16 ph = (f32x16)(0.f);
            ph = MF(A0.v, B0.v, ph);
            ph = MF(A1.v, B1.v, ph);
#pragma unroll
            for (int r = 0; r < 16; ++r) atomicAdd(&s1[h][r][lane], ph[r]);
            __builtin_amdgcn_wave_barrier();
        }
    }
    __syncthreads();
    float* pb = part + (long)g * 6912;
    for (int i = tid; i < 6144; i += 256) pb[i] = ((float*)s1)[i];
    for (int i = tid; i < 768;  i += 256) pb[6144 + i] = ((float*)skv)[i];
}

// ---------------- k1c: reduce 128 block-partials/batch + fold LN affine -------
// grid 24 (= b*6+h) x 1024. kvg[b,h,d,e] deterministic (no atomics).
__global__ __launch_bounds__(1024)
void k1c(const float* __restrict__ part,
         const float* __restrict__ klnw, const float* __restrict__ klnb,
         const float* __restrict__ vlnw, const float* __restrict__ vlnb,
         float* __restrict__ kvg)
{
    __shared__ float sks[32], svs[32];
    const int bh = blockIdx.x, b = bh / 6, h = bh % 6;
    const int t = threadIdx.x;
    const int d = t >> 5, e = t & 31;
    const int lhd = (d >> 2) & 1, r = (d & 3) + 4 * (d >> 3);
    const float* pb = part + (long)(b * 128) * 6912;
    const int off = h * 1024 + r * 64 + (e + 32 * lhd);
    float s = 0.f;
#pragma unroll 4
    for (int w = 0; w < 128; ++w) s += pb[(long)w * 6912 + off];
    if (t < 64) {
        int tt = t & 31;
        int o2 = 6144 + (t < 32 ? 0 : 384) + h * 64 + tt;
        float acc = 0.f;
#pragma unroll 4
        for (int w = 0; w < 128; ++w)
            acc += pb[(long)w * 6912 + o2] + pb[(long)w * 6912 + o2 + 32];
        if (t < 32) sks[tt] = acc; else svs[tt] = acc;
    }
    __syncthreads();
    float kw = klnw[h * 32 + d], kb = klnb[h * 32 + d];
    float vw = vlnw[h * 32 + e], vb = vlnb[h * 32 + e];
    float kv = (kw * vw * s + kw * vb * sks[d] + kb * vw * svs[e]) * (1.f / 65536.f)
             + kb * vb;
    kvg[((b * 6 + h) * 32 + d) * 32 + e] = kv;
}

// ---------------- k2a: Pt[b][cp][c], c0[b][cp] (fp32, exact q path) ------------
__global__ void k2a(const float* __restrict__ qkv_w, const float* __restrict__ qkv_b,
                    const float* __restrict__ kvg,
                    float* __restrict__ Pt, float* __restrict__ c0)
{
    int b = blockIdx.y;
    const float* kvb = kvg + (long)b * 6144;
    if (blockIdx.x < 144) {
        int idx = blockIdx.x * 256 + threadIdx.x;
        int c = idx % 192, cp = idx / 192;
        int h = cp >> 5, e = cp & 31;
        float s = 0.f;
#pragma unroll 8
        for (int d = 0; d < 32; ++d)
            s += qkv_w[(h * 96 + d) * 192 + c] * kvb[(h * 32 + d) * 32 + e];
        Pt[(long)b * 36864 + cp * 192 + c] = s;
    } else if (threadIdx.x < 192) {
        int cp = threadIdx.x, h = cp >> 5, e = cp & 31;
        float s = 0.f;
#pragma unroll 8
        for (int d = 0; d < 32; ++d)
            s += qkv_b[h * 96 + d] * kvb[(h * 32 + d) * 32 + e];
        c0[b * 192 + cp] = s;
    }
}

// ---------------- k2b: M1t[b][j][c], d1[b][j] ----------------------------------
__global__ void k2b(const float* __restrict__ o1w, const float* __restrict__ o1b,
                    const float* __restrict__ Pt, const float* __restrict__ c0,
                    float* __restrict__ M1t, float* __restrict__ d1)
{
    int b = blockIdx.y;
    if (blockIdx.x < 144) {
        int idx = blockIdx.x * 256 + threadIdx.x;
        int c = idx % 192, j = idx / 192;
        float s = o1w[j * 192 + c];
        const float* pb = Pt + (long)b * 36864;
        const float* wr = o1w + j * 192;
#pragma unroll 8
        for (int cp = 0; cp < 192; ++cp)
            s += pb[cp * 192 + c] * wr[cp];
        M1t[(long)b * 36864 + j * 192 + c] = s;
    } else if (threadIdx.x < 192) {
        int j = threadIdx.x;
        float s = o1b[j];
        const float* wr = o1w + j * 192;
#pragma unroll 8
        for (int cp = 0; cp < 192; ++cp)
            s += c0[b * 192 + cp] * wr[cp];
        d1[b * 192 + j] = s;
    }
}

// ---------------- k2c: pack M1t -> bf16 B-frag order ---------------------------
__global__ void k2c(const float* __restrict__ M1t, unsigned* __restrict__ M1pk)
{
    int idx = blockIdx.x * 256 + threadIdx.x;
    if (idx < 73728) {
        int b = idx / 18432, r = idx % 18432;
        int kt = r / 1536, r2 = r % 1536, jt = r2 / 256, r3 = r2 % 256;
        int l = r3 >> 2, q = r3 & 3;
        int c = kt * 16 + (l >> 5) * 8 + q * 2;
        int j = jt * 32 + (l & 31);
        const float* src = M1t + (long)b * 36864 + j * 192 + c;
        M1pk[idx] = pk(src[0], src[1]);
    }
}

// ---------------- k3: out = gelu(x@M1^T)@o2^T + o2b + x via 2x MFMA ------------
// grid 2048 x 256; wave = 32-px strip; LDS only for C->A layout transform of h.
__global__ __launch_bounds__(256, 2)
void k3(const float* __restrict__ x, const u32x4* __restrict__ M1bf,
        const float* __restrict__ d1, const u32x4* __restrict__ o2bf,
        const float* __restrict__ o2b, float* __restrict__ out)
{
    __shared__ __align__(16) unsigned short hbuf[4][32 * 200];
    const int tid = threadIdx.x;
    const int wid = tid >> 6, lane = tid & 63;
    const int col = lane & 31, lh = lane >> 5;
    const int w = blockIdx.x * 4 + wid;
    const int b = w >> 11, sp = w & 2047;

    const float* xrow = x + ((long)(b * 65536 + sp * 32)) * 192;
    const float* xr = xrow + col * 192 + lh * 8;
    FR afr[12];
#pragma unroll
    for (int kt = 0; kt < 12; ++kt) {
        f32x4 a0 = *(const f32x4*)(xr + kt * 16);
        f32x4 a1 = *(const f32x4*)(xr + kt * 16 + 4);
        afr[kt].u[0] = pk(a0.x, a0.y); afr[kt].u[1] = pk(a0.z, a0.w);
        afr[kt].u[2] = pk(a1.x, a1.y); afr[kt].u[3] = pk(a1.z, a1.w);
    }
    float d1v[6], o2bv[6];
#pragma unroll
    for (int jt = 0; jt < 6; ++jt) {
        d1v[jt]  = d1[b * 192 + jt * 32 + col];
        o2bv[jt] = o2b[jt * 32 + col];
    }

    // GEMM1: g = x @ M1^T + d1
    f32x16 acc[6];
#pragma unroll
    for (int jt = 0; jt < 6; ++jt) acc[jt] = (f32x16)(d1v[jt]);
    const u32x4* W1 = M1bf + b * 4608;
#pragma unroll
    for (int kt = 0; kt < 12; ++kt) {
        bf16x8 av = afr[kt].v;
#pragma unroll
        for (int jt = 0; jt < 6; ++jt) {
            FR bv; bv.q = W1[(kt * 6 + jt) * 64 + lane];
            acc[jt] = MF(av, bv.v, acc[jt]);
        }
    }
    // GELU -> LDS (C-layout scatter; row stride 200 shorts => conflict-free)
    unsigned short* hb = hbuf[wid];
#pragma unroll
    for (int jt = 0; jt < 6; ++jt)
#pragma unroll
        for (int r = 0; r < 16; ++r) {
            int p = (r & 3) + 4 * lh + 8 * (r >> 2);
            hb[p * 200 + jt * 32 + col] = bfr(gelu_f(acc[jt][r]));
        }
    __syncthreads();
    // h as A-frags
    i32x4 hfr[12];
#pragma unroll
    for (int kt = 0; kt < 12; ++kt)
        hfr[kt] = *(const i32x4*)&hb[col * 200 + kt * 16 + lh * 8];
    // GEMM2: o = h @ o2^T
    f32x16 acc2[6];
#pragma unroll
    for (int jt = 0; jt < 6; ++jt) acc2[jt] = (f32x16)(0.0f);
#pragma unroll
    for (int kt = 0; kt < 12; ++kt) {
        bf16x8 av = __builtin_bit_cast(bf16x8, hfr[kt]);
#pragma unroll
        for (int jt = 0; jt < 6; ++jt) {
            FR bv; bv.q = o2bf[(kt * 6 + jt) * 64 + lane];
            acc2[jt] = MF(av, bv.v, acc2[jt]);
        }
    }
    // epilogue: + o2b + x (residual, fp32-exact), C-layout stores
    float* orow = out + ((long)(b * 65536 + sp * 32)) * 192;
#pragma unroll
    for (int jt = 0; jt < 6; ++jt) {
        int j = jt * 32 + col;
#pragma unroll
        for (int r = 0; r < 16; ++r) {
            int p = (r & 3) + 4 * lh + 8 * (r >> 2);
            orow[p * 192 + j] = acc2[jt][r] + o2bv[jt] + xrow[p * 192 + j];
        }
    }
}

// ---------------- launch -------------------------------------------------------
extern "C" void kernel_launch(void* const* d_in, const int* in_sizes, int n_in,
                              void* d_out, int out_size, void* d_ws, size_t ws_size,
                              hipStream_t stream) {
    const float* x     = (const float*)d_in[0];
    const float* qkv_w = (const float*)d_in[1];
    const float* qkv_b = (const float*)d_in[2];
    const float* o1_w  = (const float*)d_in[3];
    const float* o1_b  = (const float*)d_in[4];
    const float* o2_w  = (const float*)d_in[5];
    const float* o2_b  = (const float*)d_in[6];
    const float* klnw  = (const float*)d_in[7];
    const float* klnb  = (const float*)d_in[8];
    const float* vlnw  = (const float*)d_in[9];
    const float* vlnb  = (const float*)d_in[10];
    float* out = (float*)d_out;
    float* ws  = (float*)d_ws;

    if (ws_size < (size_t)450432 * sizeof(float)) return;

    unsigned* wkvpk = (unsigned*)(ws);            // 36864 uints
    float*    bkv   = ws + 36864;                 // 384
    float*    kvg   = ws + 37248;                 // 24576
    float*    Pt    = ws + 61824;                 // 147456
    float*    c0    = ws + 209280;                // 768
    float*    M1t   = ws + 210048;                // 147456
    float*    d1    = ws + 357504;                // 768
    unsigned* M1pk  = (unsigned*)(ws + 358272);   // 73728 uints
    unsigned* o2pk  = (unsigned*)(ws + 432000);   // 18432 uints

    k0_pack<<<218, 256, 0, stream>>>(qkv_w, qkv_b, o2_w, wkvpk, o2pk, bkv);
    // d_out doubles as scratch for per-block S1/sk/sv partials (14.2 MB); k3 overwrites it.
    k1<<<512, 256, 0, stream>>>(x, (const u32x4*)wkvpk, bkv, (float*)d_out);
    k1c<<<24, 1024, 0, stream>>>((const float*)d_out, klnw, klnb, vlnw, vlnb, kvg);
    k2a<<<dim3(145, 4), 256, 0, stream>>>(qkv_w, qkv_b, kvg, Pt, c0);
    k2b<<<dim3(145, 4), 256, 0, stream>>>(o1_w, o1_b, Pt, c0, M1t, d1);
    k2c<<<288, 256, 0, stream>>>(M1t, M1pk);
    k3<<<2048, 256, 0, stream>>>(x, (const u32x4*)M1pk, d1, (const u32x4*)o2pk,
                                 o2_b, out);
}

// Round 3
// 646.892 us; speedup vs baseline: 1.1819x; 1.1819x over previous
//
#include <hip/hip_runtime.h>
#include <math.h>

typedef __attribute__((ext_vector_type(8)))  __bf16 bf16x8;
typedef __attribute__((ext_vector_type(16))) float  f32x16;
typedef __attribute__((ext_vector_type(4)))  float  f32x4;
typedef __attribute__((ext_vector_type(4)))  int    i32x4;
typedef __attribute__((ext_vector_type(4)))  unsigned u32x4;

union FR { bf16x8 v; u32x4 q; unsigned u[4]; };

__device__ inline f32x16 MF(bf16x8 a, bf16x8 b, f32x16 c) {
    return __builtin_amdgcn_mfma_f32_32x32x16_bf16(a, b, c, 0, 0, 0);
}
__device__ inline unsigned pk(float a, float b) {
    unsigned ua = (__builtin_bit_cast(unsigned, a) + 0x8000u) >> 16;
    unsigned ub = (__builtin_bit_cast(unsigned, b) + 0x8000u) >> 16;
    return ua | (ub << 16);
}
__device__ inline unsigned short bfr(float a) {
    return (unsigned short)((__builtin_bit_cast(unsigned, a) + 0x8000u) >> 16);
}
__device__ inline float ubf(unsigned short s) {
    return __builtin_bit_cast(float, (unsigned)s << 16);
}
// sum of 16 bf16 packed in two i32x4 fragments
__device__ inline float sum16(i32x4 a, i32x4 b) {
    float s = 0.f;
#pragma unroll
    for (int i = 0; i < 4; ++i) {
        unsigned ua = (unsigned)a[i], ub = (unsigned)b[i];
        s += __builtin_bit_cast(float, ua << 16);
        s += __builtin_bit_cast(float, ua & 0xffff0000u);
        s += __builtin_bit_cast(float, ub << 16);
        s += __builtin_bit_cast(float, ub & 0xffff0000u);
    }
    return s;
}
// exact-erf GELU via Abramowitz-Stegun 7.1.26 (|err| < 1.5e-7)
__device__ inline float gelu_f(float g) {
    float z  = g * 0.70710678118654752f;
    float az = fabsf(z);
    float t  = 1.0f / (1.0f + 0.3275911f * az);
    float poly = t*(0.254829592f + t*(-0.284496736f + t*(1.421413741f +
                 t*(-1.453152027f + t*1.061405429f))));
    float er = 1.0f - poly * __expf(-az * az);
    er = (z < 0.f) ? -er : er;
    return 0.5f * g * (1.0f + er);
}

// ---------------- k0: pack Wkv + o2w into MFMA frag order, pack bkv -----------
// wkvpk: [kt12][nt12][l64][q4] uints ; elem = W[nt*32+(l&31)][kt*16+(l>>5)*8+2q..+1]
// (this layout serves BOTH as B-frag of W^T and as A-frag of W — identical bits)
__global__ void k0_pack(const float* __restrict__ qkv_w, const float* __restrict__ qkv_b,
                        const float* __restrict__ o2w,
                        unsigned* __restrict__ wkvpk, unsigned* __restrict__ o2pk,
                        float* __restrict__ bkv)
{
    int idx = blockIdx.x * 256 + threadIdx.x;
    if (idx < 36864) {
        int kt = idx / 3072, r = idx % 3072, nt = r / 256, r3 = r % 256;
        int l = r3 >> 2, q = r3 & 3;
        int c  = kt * 16 + (l >> 5) * 8 + q * 2;
        int rp = nt * 32 + (l & 31);
        int row = (rp >> 6) * 96 + 32 + (rp & 63);       // k rows 32..63, v rows 64..95
        wkvpk[idx] = pk(qkv_w[row * 192 + c], qkv_w[row * 192 + c + 1]);
    } else if (idx < 55296) {
        int i2 = idx - 36864;
        int kt = i2 / 1536, r = i2 % 1536, jt = r / 256, r3 = r % 256;
        int l = r3 >> 2, q = r3 & 3;
        int jj = kt * 16 + (l >> 5) * 8 + q * 2;
        int j  = jt * 32 + (l & 31);
        o2pk[i2] = pk(o2w[j * 192 + jj], o2w[j * 192 + jj + 1]);
    } else if (idx < 55680) {
        int rp = idx - 55296;
        bkv[rp] = qkv_b[(rp >> 6) * 96 + 32 + (rp & 63)];
    }
}

// ---------------- k1: FUSED k/v proj + LN + Gram, swapped-operand MFMA --------
// grid (384 = 128 chunks x 3 head-pairs, 4 batch) x 256; block = 2 heads, 16
// strips (4/wave).  MF(A=W, B=x) -> C-layout rows=CHANNELS cols=PIXELS, so LN
// stats are lane-local (16-reg sum + shfl_xor(32)); W A-frags staged in LDS
// once per block; Gram re-frag via tiny per-wave 32x40 bf16 tile (k1b-proven
// pattern); gram + channel-sums accumulate in VGPR across strips; per-wave
// partials -> d_out scratch; k1c reduces + folds LN affine.
__global__ __launch_bounds__(256, 2)
void k1(const float* __restrict__ x, const u32x4* __restrict__ Wpk,
        const float* __restrict__ bkv, float* __restrict__ part)
{
    __shared__ __align__(16) u32x4 Wlds[12][4][64];         // 49152 B
    __shared__ __align__(16) float biasl[2][2][2][16];      //   512 B [hi][kv][lh][r]
    __shared__ __align__(16) unsigned short tr[4][32][40];  // 10240 B per-wave tile

    const int tid = threadIdx.x;
    const int wid = tid >> 6, lane = tid & 63;
    const int col = lane & 31, lh = lane >> 5;
    const int bx = blockIdx.x, b = blockIdx.y;
    const int chunk = bx / 3, hp = bx % 3;     // hp-adjacent dispatch: x L2/L3 reuse

    // stage W A-frags for this head-pair (nt = hp*4 .. hp*4+3)
    for (int i = tid; i < 3072; i += 256) {
        int kt = i >> 8, ntl = (i >> 6) & 3, l = i & 63;
        Wlds[kt][ntl][l] = Wpk[(kt * 12 + hp * 4 + ntl) * 64 + l];
    }
    if (tid < 128) {
        int hi = tid >> 6, kv = (tid >> 5) & 1, lhh = (tid >> 4) & 1, r = tid & 15;
        int c = (r & 3) + 8 * (r >> 2) + 4 * lhh;           // C-layout row for (r,lh)
        biasl[hi][kv][lhh][r] = bkv[(hp * 4 + hi * 2 + kv) * 32 + c];
    }
    __syncthreads();

    f32x16 gram[2] = { (f32x16)(0.f), (f32x16)(0.f) };
    float ska[2] = {0.f, 0.f}, sva[2] = {0.f, 0.f};
    unsigned short* tw = &tr[wid][0][0];

    for (int it = 0; it < 4; ++it) {
        const int sp = chunk * 16 + wid * 4 + it;
        const float* xr = x + ((long)(b * 65536 + sp * 32 + col)) * 192 + lh * 8;
        FR afr[12];
#pragma unroll
        for (int kt = 0; kt < 12; ++kt) {
            f32x4 a0 = *(const f32x4*)(xr + kt * 16);
            f32x4 a1 = *(const f32x4*)(xr + kt * 16 + 4);
            afr[kt].u[0] = pk(a0.x, a0.y); afr[kt].u[1] = pk(a0.z, a0.w);
            afr[kt].u[2] = pk(a1.x, a1.y); afr[kt].u[3] = pk(a1.z, a1.w);
        }
#pragma unroll
        for (int hi = 0; hi < 2; ++hi) {
            // ---- projection: D[row=channel][col=pixel] ----
            f32x16 acck = (f32x16)(0.f), accv = (f32x16)(0.f);
#pragma unroll
            for (int kt = 0; kt < 12; ++kt) {
                FR wk, wv;
                wk.q = Wlds[kt][hi * 2][lane];
                wv.q = Wlds[kt][hi * 2 + 1][lane];
                acck = MF(wk.v, afr[kt].v, acck);
                accv = MF(wv.v, afr[kt].v, accv);
            }
            f32x4 bk[4], bv[4];
#pragma unroll
            for (int q = 0; q < 4; ++q) {
                bk[q] = *(const f32x4*)&biasl[hi][0][lh][q * 4];
                bv[q] = *(const f32x4*)&biasl[hi][1][lh][q * 4];
            }
            // ---- k: bias + lane-local stats (pixel = this lane's col) ----
            float s = 0.f, s2 = 0.f;
#pragma unroll
            for (int r = 0; r < 16; ++r) {
                acck[r] += bk[r >> 2][r & 3];
                s += acck[r]; s2 = fmaf(acck[r], acck[r], s2);
            }
            s  += __shfl_xor(s, 32);
            s2 += __shfl_xor(s2, 32);
            float m   = s * (1.f / 32.f);
            float var = fmaxf((s2 - 32.f * m * m) * (1.f / 31.f), 0.f);
            float inv = 1.f / (sqrtf(var) + 1e-5f);
            // ---- k' -> tile [ch][px pad40], then A-frags ----
            __builtin_amdgcn_wave_barrier();
#pragma unroll
            for (int r = 0; r < 16; ++r) {
                int c = (r & 3) + 8 * (r >> 2) + 4 * lh;
                tw[c * 40 + col] = bfr((acck[r] - m) * inv);
            }
            __builtin_amdgcn_wave_barrier();
            i32x4 kA0 = *(const i32x4*)&tw[col * 40 + lh * 8];
            i32x4 kA1 = *(const i32x4*)&tw[col * 40 + 16 + lh * 8];
            float rk = sum16(kA0, kA1);          // 16 px of channel col (this lh)
            rk += __shfl_xor(rk, 32);            // all 32 px
            ska[hi] += rk;
            __builtin_amdgcn_wave_barrier();     // frag reads done before overwrite
            // ---- v: bias + stats ----
            s = 0.f; s2 = 0.f;
#pragma unroll
            for (int r = 0; r < 16; ++r) {
                accv[r] += bv[r >> 2][r & 3];
                s += accv[r]; s2 = fmaf(accv[r], accv[r], s2);
            }
            s  += __shfl_xor(s, 32);
            s2 += __shfl_xor(s2, 32);
            float m2   = s * (1.f / 32.f);
            float var2 = fmaxf((s2 - 32.f * m2 * m2) * (1.f / 31.f), 0.f);
            float inv2 = 1.f / (sqrtf(var2) + 1e-5f);
#pragma unroll
            for (int r = 0; r < 16; ++r) {
                int c = (r & 3) + 8 * (r >> 2) + 4 * lh;
                tw[c * 40 + col] = bfr((accv[r] - m2) * inv2);
            }
            __builtin_amdgcn_wave_barrier();
            i32x4 vB0 = *(const i32x4*)&tw[col * 40 + lh * 8];
            i32x4 vB1 = *(const i32x4*)&tw[col * 40 + 16 + lh * 8];
            float rv = sum16(vB0, vB1);
            rv += __shfl_xor(rv, 32);
            sva[hi] += rv;
            // ---- gram += k'^T v' over the 32 pixels ----
            gram[hi] = MF(__builtin_bit_cast(bf16x8, kA0),
                          __builtin_bit_cast(bf16x8, vB0), gram[hi]);
            gram[hi] = MF(__builtin_bit_cast(bf16x8, kA1),
                          __builtin_bit_cast(bf16x8, vB1), gram[hi]);
            __builtin_amdgcn_wave_barrier();     // reads done before next writes
        }
    }
    // per-wave partial: [hi][gram 16x64][then sk/sv]
    const int widx = ((b * 3 + hp) * 128 + chunk) * 4 + wid;
    float* pb = part + (long)widx * 2176;
#pragma unroll
    for (int hi = 0; hi < 2; ++hi) {
#pragma unroll
        for (int r = 0; r < 16; ++r)
            pb[hi * 1024 + r * 64 + lane] = gram[hi][r];
        if (lh == 0) {
            pb[2048 + hi * 64 + col]      = ska[hi];
            pb[2048 + hi * 64 + 32 + col] = sva[hi];
        }
    }
}

// ---------------- k1c: reduce 512 wave-partials/(b,h) + fold LN affine --------
// grid 24 (= b*6+h) x 1024. kvg[b,h,d,e] deterministic (no atomics).
__global__ __launch_bounds__(1024)
void k1c(const float* __restrict__ part,
         const float* __restrict__ klnw, const float* __restrict__ klnb,
         const float* __restrict__ vlnw, const float* __restrict__ vlnb,
         float* __restrict__ kvg)
{
    __shared__ float sks[32], svs[32];
    const int bh = blockIdx.x, b = bh / 6, h = bh % 6;
    const int hp = h >> 1, hi = h & 1;
    const int t = threadIdx.x;
    const int d = t >> 5, e = t & 31;
    const int lhd = (d >> 2) & 1, r = (d & 3) + 4 * (d >> 3);
    const long p0 = (long)(b * 3 + hp) * 512;
    const int off = hi * 1024 + r * 64 + (e + 32 * lhd);
    float s = 0.f;
#pragma unroll 4
    for (int w = 0; w < 512; ++w) s += part[(p0 + w) * 2176 + off];
    if (t < 64) {
        int tt = t & 31;
        int o2 = 2048 + hi * 64 + (t >> 5) * 32 + tt;
        float acc = 0.f;
#pragma unroll 4
        for (int w = 0; w < 512; ++w) acc += part[(p0 + w) * 2176 + o2];
        if (t < 32) sks[tt] = acc; else svs[tt] = acc;
    }
    __syncthreads();
    float kw = klnw[h * 32 + d], kb = klnb[h * 32 + d];
    float vw = vlnw[h * 32 + e], vb = vlnb[h * 32 + e];
    float kv = (kw * vw * s + kw * vb * sks[d] + kb * vw * svs[e]) * (1.f / 65536.f)
             + kb * vb;
    kvg[((b * 6 + h) * 32 + d) * 32 + e] = kv;
}

// ---------------- k2a: Pt[b][cp][c], c0[b][cp] (fp32, exact q path) ------------
__global__ void k2a(const float* __restrict__ qkv_w, const float* __restrict__ qkv_b,
                    const float* __restrict__ kvg,
                    float* __restrict__ Pt, float* __restrict__ c0)
{
    int b = blockIdx.y;
    const float* kvb = kvg + (long)b * 6144;
    if (blockIdx.x < 144) {
        int idx = blockIdx.x * 256 + threadIdx.x;
        int c = idx % 192, cp = idx / 192;
        int h = cp >> 5, e = cp & 31;
        float s = 0.f;
#pragma unroll 8
        for (int d = 0; d < 32; ++d)
            s += qkv_w[(h * 96 + d) * 192 + c] * kvb[(h * 32 + d) * 32 + e];
        Pt[(long)b * 36864 + cp * 192 + c] = s;
    } else if (threadIdx.x < 192) {
        int cp = threadIdx.x, h = cp >> 5, e = cp & 31;
        float s = 0.f;
#pragma unroll 8
        for (int d = 0; d < 32; ++d)
            s += qkv_b[h * 96 + d] * kvb[(h * 32 + d) * 32 + e];
        c0[b * 192 + cp] = s;
    }
}

// ---------------- k2b: M1t[b][j][c], d1[b][j] ----------------------------------
__global__ void k2b(const float* __restrict__ o1w, const float* __restrict__ o1b,
                    const float* __restrict__ Pt, const float* __restrict__ c0,
                    float* __restrict__ M1t, float* __restrict__ d1)
{
    int b = blockIdx.y;
    if (blockIdx.x < 144) {
        int idx = blockIdx.x * 256 + threadIdx.x;
        int c = idx % 192, j = idx / 192;
        float s = o1w[j * 192 + c];
        const float* pb = Pt + (long)b * 36864;
        const float* wr = o1w + j * 192;
#pragma unroll 8
        for (int cp = 0; cp < 192; ++cp)
            s += pb[cp * 192 + c] * wr[cp];
        M1t[(long)b * 36864 + j * 192 + c] = s;
    } else if (threadIdx.x < 192) {
        int j = threadIdx.x;
        float s = o1b[j];
        const float* wr = o1w + j * 192;
#pragma unroll 8
        for (int cp = 0; cp < 192; ++cp)
            s += c0[b * 192 + cp] * wr[cp];
        d1[b * 192 + j] = s;
    }
}

// ---------------- k2c: pack M1t -> bf16 B-frag order ---------------------------
__global__ void k2c(const float* __restrict__ M1t, unsigned* __restrict__ M1pk)
{
    int idx = blockIdx.x * 256 + threadIdx.x;
    if (idx < 73728) {
        int b = idx / 18432, r = idx % 18432;
        int kt = r / 1536, r2 = r % 1536, jt = r2 / 256, r3 = r2 % 256;
        int l = r3 >> 2, q = r3 & 3;
        int c = kt * 16 + (l >> 5) * 8 + q * 2;
        int j = jt * 32 + (l & 31);
        const float* src = M1t + (long)b * 36864 + j * 192 + c;
        M1pk[idx] = pk(src[0], src[1]);
    }
}

// ---------------- k3: out = gelu(x@M1^T)@o2^T + o2b + x via 2x MFMA ------------
// grid 2048 x 256; wave = 32-px strip; LDS only for C->A layout transform of h.
__global__ __launch_bounds__(256, 2)
void k3(const float* __restrict__ x, const u32x4* __restrict__ M1bf,
        const float* __restrict__ d1, const u32x4* __restrict__ o2bf,
        const float* __restrict__ o2b, float* __restrict__ out)
{
    __shared__ __align__(16) unsigned short hbuf[4][32 * 200];
    const int tid = threadIdx.x;
    const int wid = tid >> 6, lane = tid & 63;
    const int col = lane & 31, lh = lane >> 5;
    const int w = blockIdx.x * 4 + wid;
    const int b = w >> 11, sp = w & 2047;

    const float* xrow = x + ((long)(b * 65536 + sp * 32)) * 192;
    const float* xr = xrow + col * 192 + lh * 8;
    FR afr[12];
#pragma unroll
    for (int kt = 0; kt < 12; ++kt) {
        f32x4 a0 = *(const f32x4*)(xr + kt * 16);
        f32x4 a1 = *(const f32x4*)(xr + kt * 16 + 4);
        afr[kt].u[0] = pk(a0.x, a0.y); afr[kt].u[1] = pk(a0.z, a0.w);
        afr[kt].u[2] = pk(a1.x, a1.y); afr[kt].u[3] = pk(a1.z, a1.w);
    }
    float d1v[6], o2bv[6];
#pragma unroll
    for (int jt = 0; jt < 6; ++jt) {
        d1v[jt]  = d1[b * 192 + jt * 32 + col];
        o2bv[jt] = o2b[jt * 32 + col];
    }

    // GEMM1: g = x @ M1^T + d1
    f32x16 acc[6];
#pragma unroll
    for (int jt = 0; jt < 6; ++jt) acc[jt] = (f32x16)(d1v[jt]);
    const u32x4* W1 = M1bf + b * 4608;
#pragma unroll
    for (int kt = 0; kt < 12; ++kt) {
        bf16x8 av = afr[kt].v;
#pragma unroll
        for (int jt = 0; jt < 6; ++jt) {
            FR bv; bv.q = W1[(kt * 6 + jt) * 64 + lane];
            acc[jt] = MF(av, bv.v, acc[jt]);
        }
    }
    // GELU -> LDS (C-layout scatter; row stride 200 shorts => conflict-free)
    unsigned short* hb = hbuf[wid];
#pragma unroll
    for (int jt = 0; jt < 6; ++jt)
#pragma unroll
        for (int r = 0; r < 16; ++r) {
            int p = (r & 3) + 4 * lh + 8 * (r >> 2);
            hb[p * 200 + jt * 32 + col] = bfr(gelu_f(acc[jt][r]));
        }
    __syncthreads();
    // h as A-frags
    i32x4 hfr[12];
#pragma unroll
    for (int kt = 0; kt < 12; ++kt)
        hfr[kt] = *(const i32x4*)&hb[col * 200 + kt * 16 + lh * 8];
    // GEMM2: o = h @ o2^T
    f32x16 acc2[6];
#pragma unroll
    for (int jt = 0; jt < 6; ++jt) acc2[jt] = (f32x16)(0.0f);
#pragma unroll
    for (int kt = 0; kt < 12; ++kt) {
        bf16x8 av = __builtin_bit_cast(bf16x8, hfr[kt]);
#pragma unroll
        for (int jt = 0; jt < 6; ++jt) {
            FR bv; bv.q = o2bf[(kt * 6 + jt) * 64 + lane];
            acc2[jt] = MF(av, bv.v, acc2[jt]);
        }
    }
    // epilogue: + o2b + x (residual, fp32-exact), C-layout stores
    float* orow = out + ((long)(b * 65536 + sp * 32)) * 192;
#pragma unroll
    for (int jt = 0; jt < 6; ++jt) {
        int j = jt * 32 + col;
#pragma unroll
        for (int r = 0; r < 16; ++r) {
            int p = (r & 3) + 4 * lh + 8 * (r >> 2);
            orow[p * 192 + j] = acc2[jt][r] + o2bv[jt] + xrow[p * 192 + j];
        }
    }
}

// ---------------- launch -------------------------------------------------------
extern "C" void kernel_launch(void* const* d_in, const int* in_sizes, int n_in,
                              void* d_out, int out_size, void* d_ws, size_t ws_size,
                              hipStream_t stream) {
    const float* x     = (const float*)d_in[0];
    const float* qkv_w = (const float*)d_in[1];
    const float* qkv_b = (const float*)d_in[2];
    const float* o1_w  = (const float*)d_in[3];
    const float* o1_b  = (const float*)d_in[4];
    const float* o2_w  = (const float*)d_in[5];
    const float* o2_b  = (const float*)d_in[6];
    const float* klnw  = (const float*)d_in[7];
    const float* klnb  = (const float*)d_in[8];
    const float* vlnw  = (const float*)d_in[9];
    const float* vlnb  = (const float*)d_in[10];
    float* out = (float*)d_out;
    float* ws  = (float*)d_ws;

    if (ws_size < (size_t)450432 * sizeof(float)) return;

    unsigned* wkvpk = (unsigned*)(ws);            // 36864 uints
    float*    bkv   = ws + 36864;                 // 384
    float*    kvg   = ws + 37248;                 // 24576
    float*    Pt    = ws + 61824;                 // 147456
    float*    c0    = ws + 209280;                // 768
    float*    M1t   = ws + 210048;                // 147456
    float*    d1    = ws + 357504;                // 768
    unsigned* M1pk  = (unsigned*)(ws + 358272);   // 73728 uints
    unsigned* o2pk  = (unsigned*)(ws + 432000);   // 18432 uints

    k0_pack<<<218, 256, 0, stream>>>(qkv_w, qkv_b, o2_w, wkvpk, o2pk, bkv);
    // d_out doubles as scratch for per-wave gram/sum partials (53.5 MB); k3 overwrites it.
    k1<<<dim3(384, 4), 256, 0, stream>>>(x, (const u32x4*)wkvpk, bkv, (float*)d_out);
    k1c<<<24, 1024, 0, stream>>>((const float*)d_out, klnw, klnb, vlnw, vlnb, kvg);
    k2a<<<dim3(145, 4), 256, 0, stream>>>(qkv_w, qkv_b, kvg, Pt, c0);
    k2b<<<dim3(145, 4), 256, 0, stream>>>(o1_w, o1_b, Pt, c0, M1t, d1);
    k2c<<<288, 256, 0, stream>>>(M1t, M1pk);
    k3<<<2048, 256, 0, stream>>>(x, (const u32x4*)M1pk, d1, (const u32x4*)o2pk,
                                 o2_b, out);
}